// Round 11
// baseline (402.219 us; speedup 1.0000x reference)
//
#include <hip/hip_runtime.h>
#include <hip/hip_bf16.h>

#define N 8192
#define D 512
#define BM 128
#define NKT 16   // K-tiles of 32

typedef __attribute__((ext_vector_type(4))) float f32x4;
typedef __attribute__((ext_vector_type(8))) short bf16x8;

__device__ __forceinline__ unsigned short f32_to_bf16(float f) {
  unsigned int u = __float_as_uint(f);
  unsigned int r = (u + 0x7fffu + ((u >> 16) & 1u)) >> 16;
  return (unsigned short)r;
}

__global__ __launch_bounds__(128) void prep_kernel(
    const float* __restrict__ X, const float* __restrict__ Y,
    unsigned short* __restrict__ Xb, unsigned short* __restrict__ Yb,
    float* __restrict__ sqX, float* __restrict__ sqY) {
  const int b = blockIdx.x;
  const int row = b & (N - 1);
  const float* src = (b < N) ? X : Y;
  unsigned short* dst = (b < N) ? Xb : Yb;
  float* sq = (b < N) ? sqX : sqY;
  const int t = threadIdx.x;
  float4 v = reinterpret_cast<const float4*>(src + (size_t)row * D)[t];
  unsigned short b0 = f32_to_bf16(v.x), b1 = f32_to_bf16(v.y),
                 b2 = f32_to_bf16(v.z), b3 = f32_to_bf16(v.w);
  float f0 = __uint_as_float((unsigned)b0 << 16);
  float f1 = __uint_as_float((unsigned)b1 << 16);
  float f2 = __uint_as_float((unsigned)b2 << 16);
  float f3 = __uint_as_float((unsigned)b3 << 16);
  float s = f0 * f0 + f1 * f1 + f2 * f2 + f3 * f3;
  ushort4 o; o.x = b0; o.y = b1; o.z = b2; o.w = b3;
  reinterpret_cast<ushort4*>(dst + (size_t)row * D)[t] = o;
  #pragma unroll
  for (int msk = 1; msk < 64; msk <<= 1) s += __shfl_xor(s, msk);
  __shared__ float red[2];
  if ((t & 63) == 0) red[t >> 6] = s;
  __syncthreads();
  if (t == 0) sq[row] = red[0] + red[1];
}

// Fused dual-GEMM + RBF + reductions — NO LDS staging. Panels are L2-resident
// (16 MB total, XCD-chunked tiles); every MFMA fragment is a contiguous
// 16B/lane global load (4 consecutive lanes = one 64B line). No barriers in
// the K-loop: waves run free, latency hidden by TLP + compiler pipelining.
__global__ __launch_bounds__(256) void hsic_main(
    const unsigned short* __restrict__ Xb, const unsigned short* __restrict__ Yb,
    const float* __restrict__ sqX, const float* __restrict__ sqY,
    float* __restrict__ rowK, float* __restrict__ rowL,
    float* __restrict__ sums) {
  // XCD chunk swizzle (T1): 2080 tiles = 8 XCDs x 260.
  const int bid = (blockIdx.x & 7) * 260 + (blockIdx.x >> 3);
  int ti = (int)((129.0f - sqrtf(16641.0f - 8.0f * (float)bid)) * 0.5f);
  while (ti > 0 && (ti * (129 - ti)) / 2 > bid) --ti;
  while (((ti + 1) * (128 - ti)) / 2 <= bid) ++ti;
  const int tj = ti + (bid - (ti * (129 - ti)) / 2);
  const bool diag = (ti == tj);

  const int ib = ti * BM, jb = tj * BM;
  const int t = threadIdx.x;
  const int lane = t & 63, wave = t >> 6;
  const int wr = wave >> 1, wc = wave & 1;     // 2x2: wave tile 64x64
  const int fr = lane & 15, fq = lane >> 4;

  f32x4 accK[4][4], accL[4][4];
  #pragma unroll
  for (int m = 0; m < 4; ++m)
    #pragma unroll
    for (int n = 0; n < 4; ++n) { accK[m][n] = (f32x4)0.f; accL[m][n] = (f32x4)0.f; }

  // Element offsets of each fragment's 16B slice at kt=0; same rows serve
  // Xb and Yb. aoff: A-side (i-panel) rows; boff: B-side (j-panel) rows.
  int aoff[4], boff[4];
  #pragma unroll
  for (int m = 0; m < 4; ++m)
    aoff[m] = (ib + wr * 64 + m * 16 + fr) * D + fq * 8;
  #pragma unroll
  for (int n = 0; n < 4; ++n)
    boff[n] = (jb + wc * 64 + n * 16 + fr) * D + fq * 8;

  #pragma unroll 1
  for (int kt = 0; kt < NKT; ++kt) {
    const int ko = kt * 32;
    bf16x8 ax[4], bx[4], ay[4], by[4];
    #pragma unroll
    for (int m = 0; m < 4; ++m)
      ax[m] = *(const bf16x8*)(Xb + aoff[m] + ko);
    #pragma unroll
    for (int n = 0; n < 4; ++n)
      bx[n] = *(const bf16x8*)(Xb + boff[n] + ko);
    #pragma unroll
    for (int m = 0; m < 4; ++m)
      ay[m] = *(const bf16x8*)(Yb + aoff[m] + ko);
    #pragma unroll
    for (int n = 0; n < 4; ++n)
      by[n] = *(const bf16x8*)(Yb + boff[n] + ko);
    __builtin_amdgcn_s_setprio(1);
    #pragma unroll
    for (int m = 0; m < 4; ++m)
      #pragma unroll
      for (int n = 0; n < 4; ++n)
        accK[m][n] = __builtin_amdgcn_mfma_f32_16x16x32_bf16(ax[m], bx[n], accK[m][n], 0, 0, 0);
    #pragma unroll
    for (int m = 0; m < 4; ++m)
      #pragma unroll
      for (int n = 0; n < 4; ++n)
        accL[m][n] = __builtin_amdgcn_mfma_f32_16x16x32_bf16(ay[m], by[n], accL[m][n], 0, 0, 0);
    __builtin_amdgcn_s_setprio(0);
  }

  // Epilogue: K = exp(-0.5*max(sq_i + sq_j - 2*G, 0)); off-diag tiles weight 2
  // and contribute column sums.
  float sxj[4], syj[4];
  #pragma unroll
  for (int n = 0; n < 4; ++n) {
    const int j = jb + wc * 64 + n * 16 + fr;
    sxj[n] = sqX[j];
    syj[n] = sqY[j];
  }
  float kl = 0.f;
  float ckK[4] = {0.f, 0.f, 0.f, 0.f}, ckL[4] = {0.f, 0.f, 0.f, 0.f};
  #pragma unroll
  for (int m = 0; m < 4; ++m) {
    #pragma unroll
    for (int r = 0; r < 4; ++r) {
      const int i = ib + wr * 64 + m * 16 + fq * 4 + r;
      const float sxi = sqX[i], syi = sqY[i];
      float rk = 0.f, rl = 0.f;
      #pragma unroll
      for (int n = 0; n < 4; ++n) {
        float dK = fmaxf(sxi + sxj[n] - 2.f * accK[m][n][r], 0.f);
        float Kv = __expf(-0.5f * dK);
        float dL = fmaxf(syi + syj[n] - 2.f * accL[m][n][r], 0.f);
        float Lv = __expf(-0.5f * dL);
        kl += Kv * Lv;
        rk += Kv; rl += Lv;
        ckK[n] += Kv; ckL[n] += Lv;
      }
      #pragma unroll
      for (int msk = 1; msk < 16; msk <<= 1) {
        rk += __shfl_xor(rk, msk);
        rl += __shfl_xor(rl, msk);
      }
      if (fr == 0) {
        atomicAdd(&rowK[i], rk);
        atomicAdd(&rowL[i], rl);
      }
    }
  }
  if (!diag) {
    #pragma unroll
    for (int n = 0; n < 4; ++n) {
      float a2 = ckK[n], b2 = ckL[n];
      a2 += __shfl_xor(a2, 16); a2 += __shfl_xor(a2, 32);
      b2 += __shfl_xor(b2, 16); b2 += __shfl_xor(b2, 32);
      if (fq == 0) {
        const int j = jb + wc * 64 + n * 16 + fr;
        atomicAdd(&rowK[j], a2);
        atomicAdd(&rowL[j], b2);
      }
    }
    kl *= 2.f;
  }
  #pragma unroll
  for (int msk = 1; msk < 64; msk <<= 1) kl += __shfl_xor(kl, msk);
  __shared__ float klred[4];
  if (lane == 0) klred[wave] = kl;
  __syncthreads();
  if (t == 0) atomicAdd(sums, klred[0] + klred[1] + klred[2] + klred[3]);
}

__global__ __launch_bounds__(256) void finalize_kernel(
    const float* __restrict__ rowK, const float* __restrict__ rowL,
    const float* __restrict__ sums, float* __restrict__ out) {
  const int t = threadIdx.x;
  float dp = 0.f, sk = 0.f, sl = 0.f;
  for (int i = t; i < N; i += 256) {
    float a = rowK[i], b = rowL[i];
    dp += a * b; sk += a; sl += b;
  }
  #pragma unroll
  for (int msk = 1; msk < 64; msk <<= 1) {
    dp += __shfl_xor(dp, msk);
    sk += __shfl_xor(sk, msk);
    sl += __shfl_xor(sl, msk);
  }
  __shared__ float r[3][4];
  const int wave = t >> 6, lane = t & 63;
  if (lane == 0) { r[0][wave] = dp; r[1][wave] = sk; r[2][wave] = sl; }
  __syncthreads();
  if (t == 0) {
    float DP = r[0][0] + r[0][1] + r[0][2] + r[0][3];
    float SK = r[1][0] + r[1][1] + r[1][2] + r[1][3];
    float SL = r[2][0] + r[2][1] + r[2][2] + r[2][3];
    const float n = (float)N;
    float raw = sums[0] - (2.f / n) * DP + (SK / n) * (SL / n);
    out[0] = raw / ((n - 1.f) * (n - 1.f));
  }
}

extern "C" void kernel_launch(void* const* d_in, const int* in_sizes, int n_in,
                              void* d_out, int out_size, void* d_ws, size_t ws_size,
                              hipStream_t stream) {
  const float* X = (const float*)d_in[0];
  const float* Y = (const float*)d_in[1];
  char* ws = (char*)d_ws;
  unsigned short* Xb = (unsigned short*)ws;                       // 8 MB
  unsigned short* Yb = (unsigned short*)(ws + (size_t)N * D * 2); // 8 MB
  float* sqX = (float*)(ws + (size_t)N * D * 4);
  float* sqY = sqX + N;
  float* rowK = sqY + N;
  float* rowL = rowK + N;
  float* sums = rowL + N;

  hipMemsetAsync(rowK, 0, (size_t)(2 * N + 16) * sizeof(float), stream);
  prep_kernel<<<2 * N, 128, 0, stream>>>(X, Y, Xb, Yb, sqX, sqY);
  const int ntiles = (N / BM) * (N / BM + 1) / 2;  // 2080 upper-triangle tiles
  hsic_main<<<ntiles, 256, 0, stream>>>(Xb, Yb, sqX, sqY, rowK, rowL, sums);
  finalize_kernel<<<1, 256, 0, stream>>>(rowK, rowL, sums, (float*)d_out);
}

// Round 12
// 288.986 us; speedup vs baseline: 1.3918x; 1.3918x over previous
//
#include <hip/hip_runtime.h>
#include <hip/hip_bf16.h>

#define N 8192
#define D 512
#define NKT 16   // K-tiles of 32

typedef __attribute__((ext_vector_type(4))) float f32x4;
typedef __attribute__((ext_vector_type(8))) short bf16x8;

__device__ __forceinline__ void g2l16(const void* g, void* l) {
  __builtin_amdgcn_global_load_lds(
      (const __attribute__((address_space(1))) void*)g,
      (__attribute__((address_space(3))) void*)l, 16, 0, 0);
}

__device__ __forceinline__ unsigned short f32_to_bf16(float f) {
  unsigned int u = __float_as_uint(f);
  unsigned int r = (u + 0x7fffu + ((u >> 16) & 1u)) >> 16;
  return (unsigned short)r;
}

// XOR-swizzled LDS element offset for [row][32 bf16] tiles (row stride 64B).
// swz(row)=(((row>>1)&3)<<4): 2-way bank aliasing only (free per m136).
__device__ __forceinline__ int lds_off(int row, int kobyte) {
  return row * 32 + ((kobyte ^ (((row >> 1) & 3) << 4)) >> 1);
}

__global__ __launch_bounds__(128) void prep_kernel(
    const float* __restrict__ X, const float* __restrict__ Y,
    unsigned short* __restrict__ Xb, unsigned short* __restrict__ Yb,
    float* __restrict__ sqX, float* __restrict__ sqY) {
  const int b = blockIdx.x;
  const int row = b & (N - 1);
  const float* src = (b < N) ? X : Y;
  unsigned short* dst = (b < N) ? Xb : Yb;
  float* sq = (b < N) ? sqX : sqY;
  const int t = threadIdx.x;
  float4 v = reinterpret_cast<const float4*>(src + (size_t)row * D)[t];
  unsigned short b0 = f32_to_bf16(v.x), b1 = f32_to_bf16(v.y),
                 b2 = f32_to_bf16(v.z), b3 = f32_to_bf16(v.w);
  float f0 = __uint_as_float((unsigned)b0 << 16);
  float f1 = __uint_as_float((unsigned)b1 << 16);
  float f2 = __uint_as_float((unsigned)b2 << 16);
  float f3 = __uint_as_float((unsigned)b3 << 16);
  float s = f0 * f0 + f1 * f1 + f2 * f2 + f3 * f3;
  ushort4 o; o.x = b0; o.y = b1; o.z = b2; o.w = b3;
  reinterpret_cast<ushort4*>(dst + (size_t)row * D)[t] = o;
  #pragma unroll
  for (int msk = 1; msk < 64; msk <<= 1) s += __shfl_xor(s, msk);
  __shared__ float red[2];
  if ((t & 63) == 0) red[t >> 6] = s;
  __syncthreads();
  if (t == 0) sq[row] = red[0] + red[1];
}

// Fused dual-GEMM + RBF + reductions. SMALL BLOCKS: 2 waves, tile 128x64,
// wave tile 64x64 per matrix (acc 128 regs -> ~180 total -> 2 waves/SIMD ->
// 8 waves/CU = 4 INDEPENDENT blocks/CU for cross-block stall overlap).
// BK=32 single-buffered: LDS 24KB/block (4 blocks -> 96KB/CU).
__global__ __launch_bounds__(128) void hsic_main(
    const unsigned short* __restrict__ Xb, const unsigned short* __restrict__ Yb,
    const float* __restrict__ sqX, const float* __restrict__ sqY,
    float* __restrict__ rowK, float* __restrict__ rowL,
    float* __restrict__ sums) {
  __shared__ __align__(16) unsigned short sAx[128 * 32];  // 8KB  i-panel X
  __shared__ __align__(16) unsigned short sBx[64 * 32];   // 4KB  j-panel X
  __shared__ __align__(16) unsigned short sAy[128 * 32];  // 8KB  i-panel Y
  __shared__ __align__(16) unsigned short sBy[64 * 32];   // 4KB  j-panel Y

  // 4160 tiles (128-row x 64-col, upper triangle: tjc >= 2*ti) = 8 XCDs x 520.
  const int bid = (blockIdx.x & 7) * 520 + (blockIdx.x >> 3);
  // cnt(ti) = ti*(129-ti) tiles before row-block ti.
  int ti = (int)((129.0f - sqrtf(16641.0f - 4.0f * (float)bid)) * 0.5f);
  while (ti > 0 && ti * (129 - ti) > bid) --ti;
  while ((ti + 1) * (128 - ti) <= bid) ++ti;
  const int tjc = 2 * ti + (bid - ti * (129 - ti));
  const bool w2 = (tjc >= 2 * ti + 2);   // weight-2 (mirror not materialized)

  const int ib = ti * 128, jb = tjc * 64;
  const int t = threadIdx.x;
  const int lane = t & 63, wave = t >> 6;   // 2 waves
  const int fr = lane & 15, fq = lane >> 4;

  f32x4 accK[4][4], accL[4][4];
  #pragma unroll
  for (int m = 0; m < 4; ++m)
    #pragma unroll
    for (int n = 0; n < 4; ++n) { accK[m][n] = (f32x4)0.f; accL[m][n] = (f32x4)0.f; }

  const unsigned short* s0 = Xb + (size_t)ib * D;
  const unsigned short* s1 = Xb + (size_t)jb * D;
  const unsigned short* s2 = Yb + (size_t)ib * D;
  const unsigned short* s3 = Yb + (size_t)jb * D;

  // Stage mapping: 128 threads x 16B = 2KB = 32 rows x 32 cols per issue.
  // row = q*32 + t/4, colbyte = (t&3)*16, source pre-swizzled; swz bits
  // = (row>>1)&3 = (t>>3)&3, q-independent (q*32 doesn't touch those bits).
  const int srow = t >> 2;
  const int swcb = ((t & 3) * 16) ^ (((t >> 3) & 3) << 4);
  const int loff = t * 8;

  // 12 vmem issues per stage call.
  auto stage = [&](int kt) {
    const int kb = kt * 32;
    #pragma unroll
    for (int q = 0; q < 4; ++q) {
      const size_t goff = (size_t)(q * 32 + srow) * D + kb + (swcb >> 1);
      const int lo = q * 1024 + loff;
      g2l16(s0 + goff, &sAx[lo]);
      g2l16(s2 + goff, &sAy[lo]);
      if (q < 2) {
        g2l16(s1 + goff, &sBx[lo]);
        g2l16(s3 + goff, &sBy[lo]);
      }
    }
  };

  #pragma unroll 1
  for (int kt = 0; kt < NKT; ++kt) {
    stage(kt);
    __syncthreads();
    const int kob = fq * 16;
    {
      bf16x8 a[4], b[4];
      #pragma unroll
      for (int m = 0; m < 4; ++m)
        a[m] = *(const bf16x8*)&sAx[lds_off(wave * 64 + m * 16 + fr, kob)];
      #pragma unroll
      for (int n = 0; n < 4; ++n)
        b[n] = *(const bf16x8*)&sBx[lds_off(n * 16 + fr, kob)];
      __builtin_amdgcn_s_setprio(1);
      #pragma unroll
      for (int m = 0; m < 4; ++m)
        #pragma unroll
        for (int n = 0; n < 4; ++n)
          accK[m][n] = __builtin_amdgcn_mfma_f32_16x16x32_bf16(a[m], b[n], accK[m][n], 0, 0, 0);
      __builtin_amdgcn_s_setprio(0);
    }
    {
      bf16x8 a[4], b[4];
      #pragma unroll
      for (int m = 0; m < 4; ++m)
        a[m] = *(const bf16x8*)&sAy[lds_off(wave * 64 + m * 16 + fr, kob)];
      #pragma unroll
      for (int n = 0; n < 4; ++n)
        b[n] = *(const bf16x8*)&sBy[lds_off(n * 16 + fr, kob)];
      __builtin_amdgcn_s_setprio(1);
      #pragma unroll
      for (int m = 0; m < 4; ++m)
        #pragma unroll
        for (int n = 0; n < 4; ++n)
          accL[m][n] = __builtin_amdgcn_mfma_f32_16x16x32_bf16(a[m], b[n], accL[m][n], 0, 0, 0);
      __builtin_amdgcn_s_setprio(0);
    }
    __syncthreads();
  }

  // Epilogue: K = exp(-0.5*max(sq_i + sq_j - 2*G, 0)). Weight-2 tiles stand
  // for both (i,j) and (j,i): kl doubled, column sums -> rowK/rowL[j].
  float sxj[4], syj[4];
  #pragma unroll
  for (int n = 0; n < 4; ++n) {
    const int j = jb + n * 16 + fr;
    sxj[n] = sqX[j];
    syj[n] = sqY[j];
  }
  float kl = 0.f;
  float ckK[4] = {0.f, 0.f, 0.f, 0.f}, ckL[4] = {0.f, 0.f, 0.f, 0.f};
  #pragma unroll
  for (int m = 0; m < 4; ++m) {
    #pragma unroll
    for (int r = 0; r < 4; ++r) {
      const int i = ib + wave * 64 + m * 16 + fq * 4 + r;
      const float sxi = sqX[i], syi = sqY[i];
      float rk = 0.f, rl = 0.f;
      #pragma unroll
      for (int n = 0; n < 4; ++n) {
        float dK = fmaxf(sxi + sxj[n] - 2.f * accK[m][n][r], 0.f);
        float Kv = __expf(-0.5f * dK);
        float dL = fmaxf(syi + syj[n] - 2.f * accL[m][n][r], 0.f);
        float Lv = __expf(-0.5f * dL);
        kl += Kv * Lv;
        rk += Kv; rl += Lv;
        ckK[n] += Kv; ckL[n] += Lv;
      }
      #pragma unroll
      for (int msk = 1; msk < 16; msk <<= 1) {
        rk += __shfl_xor(rk, msk);
        rl += __shfl_xor(rl, msk);
      }
      if (fr == 0) {
        atomicAdd(&rowK[i], rk);
        atomicAdd(&rowL[i], rl);
      }
    }
  }
  if (w2) {
    #pragma unroll
    for (int n = 0; n < 4; ++n) {
      float a2 = ckK[n], b2 = ckL[n];
      a2 += __shfl_xor(a2, 16); a2 += __shfl_xor(a2, 32);
      b2 += __shfl_xor(b2, 16); b2 += __shfl_xor(b2, 32);
      if (fq == 0) {
        const int j = jb + n * 16 + fr;
        atomicAdd(&rowK[j], a2);
        atomicAdd(&rowL[j], b2);
      }
    }
    kl *= 2.f;
  }
  #pragma unroll
  for (int msk = 1; msk < 64; msk <<= 1) kl += __shfl_xor(kl, msk);
  __shared__ float klred[2];
  if (lane == 0) klred[wave] = kl;
  __syncthreads();
  if (t == 0) atomicAdd(sums, klred[0] + klred[1]);
}

__global__ __launch_bounds__(256) void finalize_kernel(
    const float* __restrict__ rowK, const float* __restrict__ rowL,
    const float* __restrict__ sums, float* __restrict__ out) {
  const int t = threadIdx.x;
  float dp = 0.f, sk = 0.f, sl = 0.f;
  for (int i = t; i < N; i += 256) {
    float a = rowK[i], b = rowL[i];
    dp += a * b; sk += a; sl += b;
  }
  #pragma unroll
  for (int msk = 1; msk < 64; msk <<= 1) {
    dp += __shfl_xor(dp, msk);
    sk += __shfl_xor(sk, msk);
    sl += __shfl_xor(sl, msk);
  }
  __shared__ float r[3][4];
  const int wave = t >> 6, lane = t & 63;
  if (lane == 0) { r[0][wave] = dp; r[1][wave] = sk; r[2][wave] = sl; }
  __syncthreads();
  if (t == 0) {
    float DP = r[0][0] + r[0][1] + r[0][2] + r[0][3];
    float SK = r[1][0] + r[1][1] + r[1][2] + r[1][3];
    float SL = r[2][0] + r[2][1] + r[2][2] + r[2][3];
    const float n = (float)N;
    float raw = sums[0] - (2.f / n) * DP + (SK / n) * (SL / n);
    out[0] = raw / ((n - 1.f) * (n - 1.f));
  }
}

extern "C" void kernel_launch(void* const* d_in, const int* in_sizes, int n_in,
                              void* d_out, int out_size, void* d_ws, size_t ws_size,
                              hipStream_t stream) {
  const float* X = (const float*)d_in[0];
  const float* Y = (const float*)d_in[1];
  char* ws = (char*)d_ws;
  unsigned short* Xb = (unsigned short*)ws;                       // 8 MB
  unsigned short* Yb = (unsigned short*)(ws + (size_t)N * D * 2); // 8 MB
  float* sqX = (float*)(ws + (size_t)N * D * 4);
  float* sqY = sqX + N;
  float* rowK = sqY + N;
  float* rowL = rowK + N;
  float* sums = rowL + N;

  hipMemsetAsync(rowK, 0, (size_t)(2 * N + 16) * sizeof(float), stream);
  prep_kernel<<<2 * N, 128, 0, stream>>>(X, Y, Xb, Yb, sqX, sqY);
  const int ntiles = 4160;  // 128x64 tiles covering the upper triangle
  hsic_main<<<ntiles, 128, 0, stream>>>(Xb, Yb, sqX, sqY, rowK, rowL, sums);
  finalize_kernel<<<1, 256, 0, stream>>>(rowK, rowL, sums, (float*)d_out);
}

// Round 13
// 153.977 us; speedup vs baseline: 2.6122x; 1.8768x over previous
//
#include <hip/hip_runtime.h>
#include <hip/hip_bf16.h>

#define N 8192
#define D 512
#define NKT 8    // K-groups of 64 (fp8)

typedef __attribute__((ext_vector_type(4))) float f32x4;
typedef __attribute__((ext_vector_type(2))) long i64x2;

__device__ __forceinline__ void g2l16(const void* g, void* l) {
  __builtin_amdgcn_global_load_lds(
      (const __attribute__((address_space(1))) void*)g,
      (__attribute__((address_space(3))) void*)l, 16, 0, 0);
}

// Prep: f32 -> fp8 e4m3 with k-permuted layout per 64-col group:
// chunk j (16B) = k{8j..8j+7} | k{32+8j..32+8j+7}, so one b128 LDS read
// feeds both K=32 halves of the 16x16x32 fp8 MFMA pair. sq computed from
// DEQUANTIZED values (keeps diagonal d2 exactly 0).
__global__ __launch_bounds__(128) void prep_kernel(
    const float* __restrict__ X, const float* __restrict__ Y,
    unsigned char* __restrict__ Xb, unsigned char* __restrict__ Yb,
    float* __restrict__ sqX, float* __restrict__ sqY) {
  const int b = blockIdx.x;
  const int row = b & (N - 1);
  const float* src = (b < N) ? X : Y;
  unsigned char* dst = (b < N) ? Xb : Yb;
  float* sq = (b < N) ? sqX : sqY;
  const int t = threadIdx.x;                 // 128 threads x 4 floats = 512
  float4 v = reinterpret_cast<const float4*>(src + (size_t)row * D)[t];
  unsigned p = __builtin_amdgcn_cvt_pk_fp8_f32(v.x, v.y, 0, false);
  p = __builtin_amdgcn_cvt_pk_fp8_f32(v.z, v.w, p, true);
  float f0 = __builtin_amdgcn_cvt_f32_fp8(p, 0);
  float f1 = __builtin_amdgcn_cvt_f32_fp8(p, 1);
  float f2 = __builtin_amdgcn_cvt_f32_fp8(p, 2);
  float f3 = __builtin_amdgcn_cvt_f32_fp8(p, 3);
  float s = f0 * f0 + f1 * f1 + f2 * f2 + f3 * f3;
  const int g = t >> 4;                      // 64-col group
  const int kl = (t & 15) * 4;               // k within group
  const int dest = g * 64 + ((kl & 31) >> 3) * 16 + (kl >> 5) * 8 + (kl & 7);
  *reinterpret_cast<unsigned*>(dst + (size_t)row * D + dest) = p;
  #pragma unroll
  for (int msk = 1; msk < 64; msk <<= 1) s += __shfl_xor(s, msk);
  __shared__ float red[2];
  if ((t & 63) == 0) red[t >> 6] = s;
  __syncthreads();
  if (t == 0) sq[row] = red[0] + red[1];
}

// Fused dual-GEMM (fp8) + RBF + reductions, upper-triangle tiles, R5's
// 2-phase pipeline: X-MFMAs overlap next X staging, Y-MFMAs next Y staging.
// Counted vmcnt (never 0 in-loop). LDS 32KB (half of bf16).
__global__ __launch_bounds__(256, 2) void hsic_main(
    const unsigned char* __restrict__ Xb, const unsigned char* __restrict__ Yb,
    const float* __restrict__ sqX, const float* __restrict__ sqY,
    float* __restrict__ rowK, float* __restrict__ rowL,
    float* __restrict__ sums) {
  __shared__ __align__(16) unsigned char sXi[128 * 64];
  __shared__ __align__(16) unsigned char sXj[128 * 64];
  __shared__ __align__(16) unsigned char sYi[128 * 64];
  __shared__ __align__(16) unsigned char sYj[128 * 64];

  const int bid = (blockIdx.x & 7) * 260 + (blockIdx.x >> 3);  // XCD chunks
  int ti = (int)((129.0f - sqrtf(16641.0f - 8.0f * (float)bid)) * 0.5f);
  while (ti > 0 && (ti * (129 - ti)) / 2 > bid) --ti;
  while (((ti + 1) * (128 - ti)) / 2 <= bid) ++ti;
  const int tj = ti + (bid - (ti * (129 - ti)) / 2);
  const bool diag = (ti == tj);

  const int ib = ti * 128, jb = tj * 128;
  const int t = threadIdx.x;
  const int lane = t & 63, wave = t >> 6;
  const int wr = wave >> 1, wc = wave & 1;     // 2x2 waves, 64x64 tiles
  const int fr = lane & 15, fq = lane >> 4;

  f32x4 accK[4][4], accL[4][4];
  #pragma unroll
  for (int m = 0; m < 4; ++m)
    #pragma unroll
    for (int n = 0; n < 4; ++n) { accK[m][n] = (f32x4)0.f; accL[m][n] = (f32x4)0.f; }

  const unsigned char* s0 = Xb + (size_t)ib * D;
  const unsigned char* s1 = Xb + (size_t)jb * D;
  const unsigned char* s2 = Yb + (size_t)ib * D;
  const unsigned char* s3 = Yb + (size_t)jb * D;

  // Stage: 256 threads x 16B = 4KB = 64 rows x 64B per issue; 2 issues/buffer.
  // row = q*64 + t/4, 16B-chunk = t&3, XOR-swizzled at 16B granule:
  // swz(row) = ((row>>1)&3)<<4; (row>>1)&3 = (t>>3)&3, q-independent.
  const int srow = t >> 2;
  const int swcb = ((t & 3) * 16) ^ (((t >> 3) & 3) << 4);
  const int lo16 = t * 16;

  auto stageX = [&](int kt) {      // 4 vmem issues
    #pragma unroll
    for (int q = 0; q < 2; ++q) {
      const size_t goff = (size_t)(q * 64 + srow) * D + kt * 64 + swcb;
      const int lo = q * 4096 + lo16;
      g2l16(s0 + goff, sXi + lo);
      g2l16(s1 + goff, sXj + lo);
    }
  };
  auto stageY = [&](int kt) {      // 4 vmem issues
    #pragma unroll
    for (int q = 0; q < 2; ++q) {
      const size_t goff = (size_t)(q * 64 + srow) * D + kt * 64 + swcb;
      const int lo = q * 4096 + lo16;
      g2l16(s2 + goff, sYi + lo);
      g2l16(s3 + goff, sYj + lo);
    }
  };

  // Fragment column within a row (same for all m/n): 16B chunk fq, swizzled.
  const int fcol = (fq * 16) ^ (((fr >> 1) & 3) << 4);

  i64x2 a[4], b[4];
  auto loadFrags = [&](const unsigned char* si, const unsigned char* sj) {
    #pragma unroll
    for (int m = 0; m < 4; ++m)
      a[m] = *(const i64x2*)&si[(wr * 64 + m * 16 + fr) * 64 + fcol];
    #pragma unroll
    for (int n = 0; n < 4; ++n)
      b[n] = *(const i64x2*)&sj[(wc * 64 + n * 16 + fr) * 64 + fcol];
  };
  auto mmaInto = [&](f32x4 (&acc)[4][4]) {
    __builtin_amdgcn_s_setprio(1);
    #pragma unroll
    for (int m = 0; m < 4; ++m)
      #pragma unroll
      for (int n = 0; n < 4; ++n) {
        acc[m][n] = __builtin_amdgcn_mfma_f32_16x16x32_fp8_fp8(a[m][0], b[n][0], acc[m][n], 0, 0, 0);
        acc[m][n] = __builtin_amdgcn_mfma_f32_16x16x32_fp8_fp8(a[m][1], b[n][1], acc[m][n], 0, 0, 0);
      }
    __builtin_amdgcn_s_setprio(0);
  };

  stageX(0);          // 4 in flight
  stageY(0);          // 8 in flight
  for (int kt = 0; kt < NKT - 1; ++kt) {
    // X phase: own X(kt) is the oldest 4 of 8 outstanding
    asm volatile("s_waitcnt vmcnt(4)" ::: "memory");
    __builtin_amdgcn_s_barrier();
    loadFrags(sXi, sXj);
    asm volatile("s_waitcnt lgkmcnt(0)" ::: "memory");
    __builtin_amdgcn_s_barrier();
    stageX(kt + 1);
    mmaInto(accK);
    // Y phase
    asm volatile("s_waitcnt vmcnt(4)" ::: "memory");
    __builtin_amdgcn_s_barrier();
    loadFrags(sYi, sYj);
    asm volatile("s_waitcnt lgkmcnt(0)" ::: "memory");
    __builtin_amdgcn_s_barrier();
    stageY(kt + 1);
    mmaInto(accL);
  }
  asm volatile("s_waitcnt vmcnt(4)" ::: "memory");   // X(7) done
  __builtin_amdgcn_s_barrier();
  loadFrags(sXi, sXj);
  mmaInto(accK);
  asm volatile("s_waitcnt vmcnt(0)" ::: "memory");   // Y(7) done
  __builtin_amdgcn_s_barrier();
  loadFrags(sYi, sYj);
  mmaInto(accL);

  // Epilogue: K = exp(-0.5*max(sq_i + sq_j - 2*G, 0)); off-diag tiles weight 2
  // and contribute column sums.
  float sxj[4], syj[4];
  #pragma unroll
  for (int n = 0; n < 4; ++n) {
    const int j = jb + wc * 64 + n * 16 + fr;
    sxj[n] = sqX[j];
    syj[n] = sqY[j];
  }
  float kl = 0.f;
  float ckK[4] = {0.f, 0.f, 0.f, 0.f}, ckL[4] = {0.f, 0.f, 0.f, 0.f};
  #pragma unroll
  for (int m = 0; m < 4; ++m) {
    #pragma unroll
    for (int r = 0; r < 4; ++r) {
      const int i = ib + wr * 64 + m * 16 + fq * 4 + r;
      const float sxi = sqX[i], syi = sqY[i];
      float rk = 0.f, rl = 0.f;
      #pragma unroll
      for (int n = 0; n < 4; ++n) {
        float dK = fmaxf(sxi + sxj[n] - 2.f * accK[m][n][r], 0.f);
        float Kv = __expf(-0.5f * dK);
        float dL = fmaxf(syi + syj[n] - 2.f * accL[m][n][r], 0.f);
        float Lv = __expf(-0.5f * dL);
        kl += Kv * Lv;
        rk += Kv; rl += Lv;
        ckK[n] += Kv; ckL[n] += Lv;
      }
      #pragma unroll
      for (int msk = 1; msk < 16; msk <<= 1) {
        rk += __shfl_xor(rk, msk);
        rl += __shfl_xor(rl, msk);
      }
      if (fr == 0) {
        atomicAdd(&rowK[i], rk);
        atomicAdd(&rowL[i], rl);
      }
    }
  }
  if (!diag) {
    #pragma unroll
    for (int n = 0; n < 4; ++n) {
      float a2 = ckK[n], b2 = ckL[n];
      a2 += __shfl_xor(a2, 16); a2 += __shfl_xor(a2, 32);
      b2 += __shfl_xor(b2, 16); b2 += __shfl_xor(b2, 32);
      if (fq == 0) {
        const int j = jb + wc * 64 + n * 16 + fr;
        atomicAdd(&rowK[j], a2);
        atomicAdd(&rowL[j], b2);
      }
    }
    kl *= 2.f;
  }
  #pragma unroll
  for (int msk = 1; msk < 64; msk <<= 1) kl += __shfl_xor(kl, msk);
  __shared__ float klred[4];
  if (lane == 0) klred[wave] = kl;
  __syncthreads();
  if (t == 0) atomicAdd(sums, klred[0] + klred[1] + klred[2] + klred[3]);
}

__global__ __launch_bounds__(256) void finalize_kernel(
    const float* __restrict__ rowK, const float* __restrict__ rowL,
    const float* __restrict__ sums, float* __restrict__ out) {
  const int t = threadIdx.x;
  float dp = 0.f, sk = 0.f, sl = 0.f;
  for (int i = t; i < N; i += 256) {
    float a = rowK[i], b = rowL[i];
    dp += a * b; sk += a; sl += b;
  }
  #pragma unroll
  for (int msk = 1; msk < 64; msk <<= 1) {
    dp += __shfl_xor(dp, msk);
    sk += __shfl_xor(sk, msk);
    sl += __shfl_xor(sl, msk);
  }
  __shared__ float r[3][4];
  const int wave = t >> 6, lane = t & 63;
  if (lane == 0) { r[0][wave] = dp; r[1][wave] = sk; r[2][wave] = sl; }
  __syncthreads();
  if (t == 0) {
    float DP = r[0][0] + r[0][1] + r[0][2] + r[0][3];
    float SK = r[1][0] + r[1][1] + r[1][2] + r[1][3];
    float SL = r[2][0] + r[2][1] + r[2][2] + r[2][3];
    const float n = (float)N;
    float raw = sums[0] - (2.f / n) * DP + (SK / n) * (SL / n);
    out[0] = raw / ((n - 1.f) * (n - 1.f));
  }
}

extern "C" void kernel_launch(void* const* d_in, const int* in_sizes, int n_in,
                              void* d_out, int out_size, void* d_ws, size_t ws_size,
                              hipStream_t stream) {
  const float* X = (const float*)d_in[0];
  const float* Y = (const float*)d_in[1];
  char* ws = (char*)d_ws;
  unsigned char* Xb = (unsigned char*)ws;                    // 4 MB
  unsigned char* Yb = (unsigned char*)(ws + (size_t)N * D);  // 4 MB
  float* sqX = (float*)(ws + (size_t)2 * N * D);
  float* sqY = sqX + N;
  float* rowK = sqY + N;
  float* rowL = rowK + N;
  float* sums = rowL + N;

  hipMemsetAsync(rowK, 0, (size_t)(2 * N + 16) * sizeof(float), stream);
  prep_kernel<<<2 * N, 128, 0, stream>>>(X, Y, Xb, Yb, sqX, sqY);
  const int ntiles = (N / 128) * (N / 128 + 1) / 2;  // 2080 triangle tiles
  hsic_main<<<ntiles, 256, 0, stream>>>(Xb, Yb, sqX, sqY, rowK, rowL, sums);
  finalize_kernel<<<1, 256, 0, stream>>>(rowK, rowL, sums, (float*)d_out);
}